// Round 1
// baseline (1850.916 us; speedup 1.0000x reference)
//
#include <hip/hip_runtime.h>
#include <hip/hip_bf16.h>
#include <hip/hip_cooperative_groups.h>

namespace cg = cooperative_groups;

#define D_DIM 1024
#define NITER 20

typedef float f32x4 __attribute__((ext_vector_type(4)));
typedef __bf16 bf16x4 __attribute__((ext_vector_type(4)));
typedef __bf16 bf16x8 __attribute__((ext_vector_type(8)));

// ---- fused Sinkhorn: exp+transpose, 20 iterations, finalize P -------------
// One cooperative launch replaces 43 dispatches (launch overhead was ~9 us
// per dispatch x 43). 256 blocks x 256 threads: all co-resident (1 block/CU).
__global__ __launch_bounds__(256)
void sinkhorn_fused(const float* __restrict__ ls, float* __restrict__ Mm,
                    float* __restrict__ Mt, float* __restrict__ r,
                    float* __restrict__ u, __bf16* __restrict__ P) {
    cg::grid_group grid = cg::this_grid();
    const int tid = threadIdx.x, bid = blockIdx.x;
    const int wave = tid >> 6, lane = tid & 63;

    // phase 1: Mm = exp(ls); Mt = Mm^T (64x64 tile per block); u = 1
    {
        __shared__ float tile[64][65];
        const int bx = (bid & 15) * 64, by = (bid >> 4) * 64;
        const int tx = tid & 63, ty = tid >> 6;  // ty in 0..3
#pragma unroll
        for (int k = 0; k < 64; k += 4) {
            int row = by + ty + k;
            float v = expf(ls[row * D_DIM + bx + tx]);
            Mm[row * D_DIM + bx + tx] = v;
            tile[ty + k][tx] = v;
        }
        if (bid == 0) {
            f32x4 one = {1.f, 1.f, 1.f, 1.f};
            ((f32x4*)u)[tid] = one;
        }
        __syncthreads();
#pragma unroll
        for (int k = 0; k < 64; k += 4) {
            int row = bx + ty + k;
            Mt[row * D_DIM + by + tx] = tile[tx][ty + k];
        }
    }
    grid.sync();

    // phase 2: 20 x { r = 1/(M u); sync; u = 1/(M^T r); sync }
    // wave-per-row, 4 rows/block; M rows hoisted to registers (loop-invariant)
    const int row = bid * 4 + wave;
    const f32x4* Ar  = (const f32x4*)(Mm + (size_t)row * D_DIM);
    const f32x4* Atr = (const f32x4*)(Mt + (size_t)row * D_DIM);
    f32x4 am[4], at[4];
#pragma unroll
    for (int q = 0; q < 4; ++q) {
        am[q] = Ar[lane + q * 64];
        at[q] = Atr[lane + q * 64];
    }
    for (int it = 0; it < NITER; ++it) {
        {
            const f32x4* xr = (const f32x4*)u;
            float s = 0.f;
#pragma unroll
            for (int q = 0; q < 4; ++q) {
                f32x4 b = xr[lane + q * 64];
                s += am[q].x * b.x + am[q].y * b.y + am[q].z * b.z + am[q].w * b.w;
            }
#pragma unroll
            for (int off = 32; off; off >>= 1) s += __shfl_down(s, off, 64);
            if (lane == 0) r[row] = 1.0f / s;
        }
        grid.sync();
        {
            const f32x4* xr = (const f32x4*)r;
            float s = 0.f;
#pragma unroll
            for (int q = 0; q < 4; ++q) {
                f32x4 b = xr[lane + q * 64];
                s += at[q].x * b.x + at[q].y * b.y + at[q].z * b.z + at[q].w * b.w;
            }
#pragma unroll
            for (int off = 32; off; off >>= 1) s += __shfl_down(s, off, 64);
            if (lane == 0) u[row] = 1.0f / s;
        }
        grid.sync();
    }

    // phase 3: P[i][j] = bf16(Mm[i][j] * r[i] * u[j]), 4 rows per block
#pragma unroll
    for (int rr = 0; rr < 4; ++rr) {
        int i = bid * 4 + rr;
        float ri = r[i];
        f32x4 m = ((const f32x4*)(Mm + (size_t)i * D_DIM))[tid];
        f32x4 uu = ((const f32x4*)u)[tid];
        bf16x4 o;
        o[0] = (__bf16)(m.x * ri * uu.x);
        o[1] = (__bf16)(m.y * ri * uu.y);
        o[2] = (__bf16)(m.z * ri * uu.z);
        o[3] = (__bf16)(m.w * ri * uu.w);
        ((bf16x4*)(P + (size_t)i * D_DIM))[tid] = o;
    }
}

// ---- GEMM: C (MxN f32) = A (MxK f32, cast->bf16) * Bt (NxK bf16)^T --------
// One block per 128-row A panel; bx loops over four 256-wide N tiles so the
// A panel is HBM-fetched once (was 4x: FETCH 1.08 GB for a 270 MB ideal).
// LDS 16B-granule XOR swizzle (slot ^= (row>>1)&3): A is reg-staged so the
// write side swizzles directly; B keeps a LINEAR global_load_lds destination
// with a pre-swizzled global source (both-sides rule), read applies same XOR.
#define BM 128
#define BN 256
#define BK 32

__global__ __launch_bounds__(256)
void gemm_a32_bt16(const float* __restrict__ A, const __bf16* __restrict__ Bt,
                   float* __restrict__ C, int Msz, int Nsz, int Ksz) {
    __shared__ __bf16 As[BM * BK];  // 8 KB
    __shared__ __bf16 Bs[BN * BK];  // 16 KB
    const int tid = threadIdx.x;
    const int wave = tid >> 6, lane = tid & 63;
    const int wm = wave >> 1, wn = wave & 1;   // 2x2 waves; wave tile 64m x 128n
    const int quad = lane >> 4, l16 = lane & 15;
    const int m0 = blockIdx.x * BM;
    const int sR = (l16 >> 1) & 3;  // frag-row swizzle key: (row>>1)&3 == (l16>>1)&3

    for (int bx = 0; bx < Nsz / BN; ++bx) {
        const int n0 = bx * BN;
        f32x4 acc[4][8] = {};
        for (int k0 = 0; k0 < Ksz; k0 += BK) {
            __syncthreads();  // previous LDS readers done
            // stage A: 128x32 f32 -> bf16, swizzled 8B-granule write
#pragma unroll
            for (int itc = 0; itc < 4; ++itc) {
                int idx = tid + itc * 256;
                int arow = idx >> 3, kq = idx & 7;
                f32x4 v = *(const f32x4*)(A + (size_t)(m0 + arow) * Ksz + k0 + kq * 4);
                bf16x4 b;
                b[0] = (__bf16)v.x; b[1] = (__bf16)v.y;
                b[2] = (__bf16)v.z; b[3] = (__bf16)v.w;
                int slot = (kq >> 1) ^ ((arow >> 1) & 3);
                *(bf16x4*)(&As[arow * BK + slot * 8 + (kq & 1) * 4]) = b;
            }
            // stage B: 256x32 bf16 via async global->LDS (16B/lane),
            // linear LDS dest, per-lane global chunk pre-swizzled
#pragma unroll
            for (int q = 0; q < 4; ++q) {
                int t = wave * 4 + q;                      // 0..15, 16 n-rows each
                int nrow = t * 16 + (lane >> 2);
                int kb = (lane & 3) ^ ((lane >> 3) & 3);   // == (lane&3) ^ ((nrow>>1)&3)
                const __bf16* g = Bt + (size_t)(n0 + nrow) * Ksz + k0 + kb * 8;
                __bf16* l = Bs + t * 512;                  // 1024 B per issue
                __builtin_amdgcn_global_load_lds(
                    (const __attribute__((address_space(1))) void*)g,
                    (__attribute__((address_space(3))) void*)l, 16, 0, 0);
            }
            __syncthreads();  // vmcnt(0)+lgkmcnt(0) drain

            bf16x8 af[4], bfr[8];
#pragma unroll
            for (int a = 0; a < 4; ++a) {
                int arow = wm * 64 + a * 16 + l16;
                af[a] = *(const bf16x8*)(&As[arow * BK + (quad ^ sR) * 8]);
            }
#pragma unroll
            for (int b = 0; b < 8; ++b) {
                int brow = wn * 128 + b * 16 + l16;
                bfr[b] = *(const bf16x8*)(&Bs[brow * BK + (quad ^ sR) * 8]);
            }
#pragma unroll
            for (int a = 0; a < 4; ++a)
#pragma unroll
                for (int b = 0; b < 8; ++b)
                    acc[a][b] = __builtin_amdgcn_mfma_f32_16x16x32_bf16(
                        af[a], bfr[b], acc[a][b], 0, 0, 0);
        }
        // epilogue: C/D layout col = l16, row = quad*4 + v
#pragma unroll
        for (int a = 0; a < 4; ++a) {
            int mg = m0 + wm * 64 + a * 16 + quad * 4;
#pragma unroll
            for (int b = 0; b < 8; ++b) {
                int ng = n0 + wn * 128 + b * 16 + l16;
#pragma unroll
                for (int v = 0; v < 4; ++v)
                    C[(size_t)(mg + v) * Nsz + ng] = acc[a][b][v];
            }
        }
    }
}

extern "C" void kernel_launch(void* const* d_in, const int* in_sizes, int n_in,
                              void* d_out, int out_size, void* d_ws, size_t ws_size,
                              hipStream_t stream) {
    const float* emb = (const float*)d_in[0];   // (B, 1024) f32
    const float* ls  = (const float*)d_in[1];   // (1024, 1024) f32
    float* out = (float*)d_out;                 // (B, 1024) f32
    char* ws = (char*)d_ws;

    float* Mm  = (float*)ws;                         // 4 MB
    float* Mt  = (float*)(ws + (4u << 20));          // 4 MB
    float* r   = (float*)(ws + (8u << 20));          // 4 KB
    float* u   = (float*)(ws + (8u << 20) + 4096);   // 4 KB
    __bf16* P  = (__bf16*)(ws + (8u << 20) + 8192);  // 2 MB

    const int B = in_sizes[0] / D_DIM;  // 65536

    void* cargs[6];
    cargs[0] = (void*)&ls;
    cargs[1] = (void*)&Mm;
    cargs[2] = (void*)&Mt;
    cargs[3] = (void*)&r;
    cargs[4] = (void*)&u;
    cargs[5] = (void*)&P;
    hipLaunchCooperativeKernel(sinkhorn_fused, dim3(256), dim3(256), cargs, 0,
                               stream);

    gemm_a32_bt16<<<dim3(B / BM), 256, 0, stream>>>(emb, P, out, B, D_DIM, D_DIM);
}

// Round 2
// 709.456 us; speedup vs baseline: 2.6089x; 2.6089x over previous
//
#include <hip/hip_runtime.h>
#include <hip/hip_bf16.h>

#define D_DIM 1024
#define NITER 20

typedef float f32x4 __attribute__((ext_vector_type(4)));
typedef __bf16 bf16x4 __attribute__((ext_vector_type(4)));
typedef __bf16 bf16x8 __attribute__((ext_vector_type(8)));

// ---- prep: M = exp(ls), Mt = M^T (tiled transpose through LDS); u = 1 ----
__global__ __launch_bounds__(1024)
void prep_exp_transpose(const float* __restrict__ ls, float* __restrict__ Mm,
                        float* __restrict__ Mt, float* __restrict__ u) {
    __shared__ float tile[64][65];
    const int tx = threadIdx.x, ty = threadIdx.y;
    const int bx = blockIdx.x * 64, by = blockIdx.y * 64;
#pragma unroll
    for (int k = 0; k < 64; k += 16) {
        int r = by + ty + k, c = bx + tx;
        float v = expf(ls[r * D_DIM + c]);
        Mm[r * D_DIM + c] = v;
        tile[ty + k][tx] = v;
    }
    if (blockIdx.x == 0 && blockIdx.y == 0) u[ty * 64 + tx] = 1.0f;
    __syncthreads();
#pragma unroll
    for (int k = 0; k < 64; k += 16) {
        int r = bx + ty + k, c = by + tx;  // transposed block
        Mt[r * D_DIM + c] = tile[tx][ty + k];
    }
}

// ---- y[i] = 1 / dot(A[i,:], x); one wave per row, 4 rows per block ----
__global__ __launch_bounds__(256)
void matvec_recip(const float* __restrict__ A, const float* __restrict__ x,
                  float* __restrict__ y) {
    const int wave = threadIdx.x >> 6, lane = threadIdx.x & 63;
    const int row = blockIdx.x * 4 + wave;
    const f32x4* Ar = (const f32x4*)(A + row * D_DIM);
    const f32x4* xr = (const f32x4*)x;
    float s = 0.f;
#pragma unroll
    for (int it = 0; it < 4; ++it) {
        f32x4 a = Ar[lane + it * 64];
        f32x4 b = xr[lane + it * 64];
        s += a.x * b.x + a.y * b.y + a.z * b.z + a.w * b.w;
    }
#pragma unroll
    for (int off = 32; off > 0; off >>= 1) s += __shfl_down(s, off, 64);
    if (lane == 0) y[row] = 1.0f / s;
}

// ---- P_bf16[i][j] = bf16(M[i][j] * r[i] * u[j]) (GEMM's BT operand) ----
__global__ __launch_bounds__(256)
void finalize_P(const float* __restrict__ Mm, const float* __restrict__ r,
                const float* __restrict__ u, __bf16* __restrict__ P) {
    const int i = blockIdx.x;
    const int t = threadIdx.x;
    const float ri = r[i];
    f32x4 m = ((const f32x4*)(Mm + i * D_DIM))[t];
    f32x4 uu = ((const f32x4*)u)[t];
    bf16x4 o;
    o[0] = (__bf16)(m.x * ri * uu.x);
    o[1] = (__bf16)(m.y * ri * uu.y);
    o[2] = (__bf16)(m.z * ri * uu.z);
    o[3] = (__bf16)(m.w * ri * uu.w);
    ((bf16x4*)(P + i * D_DIM))[t] = o;
}

// ---- GEMM: C (MxN f32) = A (MxK f32, cast->bf16) * Bt (NxK bf16)^T --------
// Round-0 structure (4096 blocks, 128x128 tile, 2-barrier k-loop) + two fixes:
//  1. XCD-grouped decode: the 8 n-tiles sharing an A-panel map to CONSECUTIVE
//     slots on the SAME XCD (f%8 = XCD under round-robin dispatch), so the
//     512 KB panel is HBM-fetched ~once into that XCD's L2 (was 4x overfetch).
//     Pure speed heuristic: any (p,t) permutation is correct.
//  2. LDS XOR swizzle (16B granule, key=(row>>1)&3): A reg-staged write is
//     swizzled directly; B keeps a LINEAR global_load_lds dest with the
//     per-lane global source chunk pre-swizzled; reads apply the same XOR.
//     Kills the 8-way ds_read_b128 bank conflict (was 1.7e7).
#define BM 128
#define BN 128
#define BK 32

__global__ __launch_bounds__(256)
void gemm_a32_bt16(const float* __restrict__ A, const __bf16* __restrict__ Bt,
                   float* __restrict__ C, int Msz, int Nsz, int Ksz) {
    __shared__ __bf16 As[BM * BK];  // 8 KB
    __shared__ __bf16 Bs[BN * BK];  // 8 KB
    const int tid = threadIdx.x;
    const int wave = tid >> 6, lane = tid & 63;
    const int wm = wave >> 1, wn = wave & 1;   // 2x2 waves, 64x64 per wave
    const int quad = lane >> 4, l16 = lane & 15;
    // decode: f -> (panel p, n-tile t) with all 8 t's of p on one XCD
    const int f = blockIdx.x;
    const int xcd = f & 7, s = f >> 3;
    const int m0 = (((s >> 3) << 3) | xcd) * BM;  // panel p = (s/8)*8 + xcd
    const int n0 = (s & 7) * BN;                  // n-tile t = s % 8
    const int sR = (l16 >> 1) & 3;  // read-side swizzle key == (row>>1)&3

    f32x4 acc[4][4] = {};

    for (int k0 = 0; k0 < Ksz; k0 += BK) {
        __syncthreads();  // previous iteration's LDS readers done
        // stage A: 128x32 f32 -> bf16, swizzled 8B-granule write
#pragma unroll
        for (int itc = 0; itc < 4; ++itc) {
            int idx = tid + itc * 256;
            int arow = idx >> 3, kq = idx & 7;
            f32x4 v = *(const f32x4*)(A + (size_t)(m0 + arow) * Ksz + k0 + kq * 4);
            bf16x4 b;
            b[0] = (__bf16)v.x; b[1] = (__bf16)v.y;
            b[2] = (__bf16)v.z; b[3] = (__bf16)v.w;
            int slot = (kq >> 1) ^ ((arow >> 1) & 3);
            *(bf16x4*)(&As[arow * BK + slot * 8 + (kq & 1) * 4]) = b;
        }
        // stage B: async global->LDS, 16B/lane, linear LDS dest,
        // global source chunk pre-swizzled: kb = (lane&3) ^ ((nrow>>1)&3)
#pragma unroll
        for (int q = 0; q < 2; ++q) {
            int t8 = wave * 2 + q;                     // 0..7, 16 n-rows each
            int nrow = t8 * 16 + (lane >> 2);
            int kb = (lane & 3) ^ ((lane >> 3) & 3);
            const __bf16* g = Bt + (size_t)(n0 + nrow) * Ksz + k0 + kb * 8;
            __bf16* l = Bs + t8 * 512;                 // 1024 B per issue
            __builtin_amdgcn_global_load_lds(
                (const __attribute__((address_space(1))) void*)g,
                (__attribute__((address_space(3))) void*)l, 16, 0, 0);
        }
        __syncthreads();  // vmcnt(0)+lgkmcnt(0) drain

        bf16x8 af[4], bfr[4];
#pragma unroll
        for (int a = 0; a < 4; ++a) {
            int arow = wm * 64 + a * 16 + l16;
            af[a] = *(const bf16x8*)(&As[arow * BK + (quad ^ sR) * 8]);
        }
#pragma unroll
        for (int b = 0; b < 4; ++b) {
            int brow = wn * 64 + b * 16 + l16;
            bfr[b] = *(const bf16x8*)(&Bs[brow * BK + (quad ^ sR) * 8]);
        }
#pragma unroll
        for (int a = 0; a < 4; ++a)
#pragma unroll
            for (int b = 0; b < 4; ++b)
                acc[a][b] = __builtin_amdgcn_mfma_f32_16x16x32_bf16(
                    af[a], bfr[b], acc[a][b], 0, 0, 0);
    }

    // epilogue: C/D layout col = lane&15, row = quad*4 + reg
#pragma unroll
    for (int a = 0; a < 4; ++a) {
        int mg = m0 + wm * 64 + a * 16 + quad * 4;
#pragma unroll
        for (int b = 0; b < 4; ++b) {
            int ng = n0 + wn * 64 + b * 16 + l16;
#pragma unroll
            for (int v = 0; v < 4; ++v)
                C[(size_t)(mg + v) * Nsz + ng] = acc[a][b][v];
        }
    }
}

extern "C" void kernel_launch(void* const* d_in, const int* in_sizes, int n_in,
                              void* d_out, int out_size, void* d_ws, size_t ws_size,
                              hipStream_t stream) {
    const float* emb = (const float*)d_in[0];   // (B, 1024) f32
    const float* ls  = (const float*)d_in[1];   // (1024, 1024) f32
    float* out = (float*)d_out;                 // (B, 1024) f32
    char* ws = (char*)d_ws;

    float* Mm  = (float*)ws;                         // 4 MB
    float* Mt  = (float*)(ws + (4u << 20));          // 4 MB
    float* r   = (float*)(ws + (8u << 20));          // 4 KB
    float* u   = (float*)(ws + (8u << 20) + 4096);   // 4 KB
    __bf16* P  = (__bf16*)(ws + (8u << 20) + 8192);  // 2 MB

    const int B = in_sizes[0] / D_DIM;  // 65536

    prep_exp_transpose<<<dim3(16, 16), dim3(64, 16), 0, stream>>>(ls, Mm, Mt, u);
    for (int it = 0; it < NITER; ++it) {
        matvec_recip<<<D_DIM / 4, 256, 0, stream>>>(Mm, u, r);   // r = 1/(M u)
        matvec_recip<<<D_DIM / 4, 256, 0, stream>>>(Mt, r, u);   // u = 1/(M^T r)
    }
    finalize_P<<<D_DIM, 256, 0, stream>>>(Mm, r, u, P);
    gemm_a32_bt16<<<dim3((B / BM) * (D_DIM / BN)), 256, 0, stream>>>(
        emb, P, out, B, D_DIM, D_DIM);
}